// Round 4
// baseline (307.653 us; speedup 1.0000x reference)
//
#include <hip/hip_runtime.h>

// SoftmaxCascade: B=8192 rows, E=4681 nodes, 8-ary implicit heap
// (children of p = 8p+1..8p+8). out[0]=1; out[i]=exp(x[i]+D[(i-1)>>3]) where
// D[g]=adj[g]+x[g]+D[parent(g)], D[0]=adj[0], adj[g]=-m-log(sum exp(x_c-m)).
//
// R6 post-mortem: 4 structurally different block-grain kernels all 92-99us,
// all pipes idle -> the shared serial {phase, barrier, phase} block structure
// caps per-CU concurrency at ~6 pipelines; device MLP ~1.4MB < 4MB needed.
// R7: wave-per-row, ZERO barriers. Key identity: AD[g]=x[g]+adj[g] (AD[0]=
// adj[0]) gives D[g] = sum of AD over the ancestor chain -> only AD[0..72]
// (levels 0-2) is ever shared; per-wave LDS = 292 B. Phase1: lane l does
// group l (and 64+l for l<9), writes AD, wave-internal lgkmcnt(0) only.
// Phase2: emit groups 0..72 from live regs. Phase3: level-3 groups are
// exactly 8 all-lane chunks g=73+64c+l, register double-buffered (static
// indices), ancestor AD via broadcast LDS reads, emit immediately.
// 24+ independent wave-pipelines/CU, ~29MB device-wide MLP.

constexpr int E   = 4681;
constexpr int ADP = 80;                 // padded per-wave AD region (floats)

// Load 8-float window x[8g+1 .. 8g+8]; S = (row+1)&3 alignment phase.
// rin + 8g+1-S is 16B-aligned. g==584 scalar (avoids OOB past row end on the
// last row); g==0,S==1 gives ap==rin exactly (row 0 safe: row0 has S=1).
template<int S>
__device__ __forceinline__ void loadwin(const float* __restrict__ rin, int g, float w[8]) {
    if (g == 584) {
        #pragma unroll
        for (int k = 0; k < 8; ++k) w[k] = rin[4673 + k];
        return;
    }
    const float* ap = rin + 8 * g + 1 - S;
    float L[12];
    const float4 A = *(const float4*)ap;
    const float4 Bv = *(const float4*)(ap + 4);
    L[0] = A.x;  L[1] = A.y;  L[2] = A.z;  L[3] = A.w;
    L[4] = Bv.x; L[5] = Bv.y; L[6] = Bv.z; L[7] = Bv.w;
    if (S != 0) {
        const float4 Cv = *(const float4*)(ap + 8);
        L[8] = Cv.x; L[9] = Cv.y; L[10] = Cv.z; L[11] = Cv.w;
    } else {
        L[8] = L[9] = L[10] = L[11] = 0.0f;      // unused when S==0
    }
    #pragma unroll
    for (int k = 0; k < 8; ++k) w[k] = L[S + k]; // S static: pure reg selects
}

__device__ __forceinline__ float group_adj(const float w[8]) {
    float m = w[0];
    #pragma unroll
    for (int k = 1; k < 8; ++k) m = fmaxf(m, w[k]);
    float s = 0.0f;
    #pragma unroll
    for (int k = 0; k < 8; ++k) s += __expf(w[k] - m);
    return -m - __logf(s);
}

// Store exp(w[k]+D) -> rout[8g+1+k], k=0..7; float index of rout+8g+1 === S
// (mod 4): natural-alignment segments. In-bounds for all g<=584.
template<int S>
__device__ __forceinline__ void emit(float* __restrict__ rout, int g,
                                     const float w[8], float D) {
    float y[8];
    #pragma unroll
    for (int k = 0; k < 8; ++k) y[k] = __expf(w[k] + D);
    float* q = rout + 8 * g + 1;
    if (S == 0) {
        *(float4*)(q)     = make_float4(y[0], y[1], y[2], y[3]);
        *(float4*)(q + 4) = make_float4(y[4], y[5], y[6], y[7]);
    } else if (S == 1) {
        q[0] = y[0];
        *(float2*)(q + 1) = make_float2(y[1], y[2]);
        *(float4*)(q + 3) = make_float4(y[3], y[4], y[5], y[6]);
        q[7] = y[7];
    } else if (S == 2) {
        *(float2*)(q)     = make_float2(y[0], y[1]);
        *(float4*)(q + 2) = make_float4(y[2], y[3], y[4], y[5]);
        *(float2*)(q + 6) = make_float2(y[6], y[7]);
    } else {
        q[0] = y[0];
        *(float4*)(q + 1) = make_float4(y[1], y[2], y[3], y[4]);
        *(float2*)(q + 5) = make_float2(y[5], y[6]);
        q[7] = y[7];
    }
}

// One level-3 chunk: group g = 73+64c+l. Prefetches chunk c+1 into wn/xn
// before computing chunk c (register double-buffer, all indices static).
// p = (g-1)>>3 = 9+8c+(l>>3) (level 2, 8-way LDS broadcast);
// pp = (p-1)>>3 = c+1 (level 1, lane-uniform). D = xg+adj + AD[p]+AD[pp]+AD0.
template<int S, int C>
__device__ __forceinline__ void step3(const float* __restrict__ rin,
                                      float* __restrict__ rout,
                                      const float* __restrict__ AD, float AD0,
                                      int l, const float w[8], float xg,
                                      float wn[8], float& xn) {
    if (C < 7) {
        const int gn = 73 + 64 * (C + 1) + l;
        loadwin<S>(rin, gn, wn);
        xn = rin[gn];
    }
    const int g = 73 + 64 * C + l;
    const float adj = group_adj(w);
    const float D = xg + adj + AD[9 + 8 * C + (l >> 3)] + AD[C + 1] + AD0;
    emit<S>(rout, g, w, D);
}

template<int S>
__device__ __forceinline__ void wave_row(const float* __restrict__ rin,
                                         float* __restrict__ rout,
                                         float* __restrict__ AD, int l) {
    // ---- phase 1: groups 0..72 (the only ones whose AD is shared) ----
    float wA[8], wB[8];
    float xB = 0.0f;
    loadwin<S>(rin, l, wA);
    const float xA = rin[l];                      // unused for l==0 (root)
    const bool hB = (l < 9);
    if (hB) { loadwin<S>(rin, 64 + l, wB); xB = rin[64 + l]; }

    const float adjA = group_adj(wA);
    const float ADa = (l == 0) ? adjA : (xA + adjA);
    AD[l] = ADa;
    float ADb = 0.0f;
    if (hB) { ADb = xB + group_adj(wB); AD[64 + l] = ADb; }
    #pragma unroll
    for (int k = 0; k < 8; ++k) {                 // pin: forbid remat/reload of
        asm volatile("" : "+v"(wA[k]));           // the windows past this point
        asm volatile("" : "+v"(wB[k]));           // (R4's reload pathology)
    }
    asm volatile("s_waitcnt lgkmcnt(0)" ::: "memory");  // wave-internal only

    // ---- phase 2: D + emit for groups 0..72 (windows still in regs) ----
    const float AD0 = AD[0];
    {
        float D;
        if (l == 0) D = ADa;                      // D[0] = adj[0]
        else {
            const int p = (l - 1) >> 3;           // 0..7
            D = ADa + AD[p] + ((p > 0) ? AD0 : 0.0f);
        }
        emit<S>(rout, l, wA, D);
    }
    if (l == 0) rout[0] = 1.0f;                   // root probability
    if (hB) {
        const int p = (63 + l) >> 3;              // 7..8 (level 1)
        emit<S>(rout, 64 + l, wB, ADb + AD[p] + AD0);
    }

    // ---- phase 3: 512 level-3 groups = exactly 8 all-lane chunks ----
    float w0[8], w1[8], x0, x1 = 0.0f;
    loadwin<S>(rin, 73 + l, w0);
    x0 = rin[73 + l];
    step3<S, 0>(rin, rout, AD, AD0, l, w0, x0, w1, x1);
    step3<S, 1>(rin, rout, AD, AD0, l, w1, x1, w0, x0);
    step3<S, 2>(rin, rout, AD, AD0, l, w0, x0, w1, x1);
    step3<S, 3>(rin, rout, AD, AD0, l, w1, x1, w0, x0);
    step3<S, 4>(rin, rout, AD, AD0, l, w0, x0, w1, x1);
    step3<S, 5>(rin, rout, AD, AD0, l, w1, x1, w0, x0);
    step3<S, 6>(rin, rout, AD, AD0, l, w0, x0, w1, x1);
    step3<S, 7>(rin, rout, AD, AD0, l, w1, x1, w0, x0);
}

__global__ __launch_bounds__(256, 6) void cascade_kernel(const float* __restrict__ in,
                                                         float* __restrict__ out,
                                                         int B) {
    __shared__ float ADs[4 * ADP];                // 1.25 KB/block
    const int tid = threadIdx.x;
    const int wv = tid >> 6, l = tid & 63;
    const int row = blockIdx.x * 4 + wv;          // one row per WAVE
    if (row >= B) return;
    const float* rin = in + (long long)row * E;
    float* rout = out + (long long)row * E;
    float* AD = ADs + wv * ADP;
    // alignment phase of this row: rowbase mod 4 = row mod 4 (E odd),
    // window/store base indices are === row+1 (mod 4). Wave-uniform switch.
    switch ((row + 1) & 3) {
        case 0: wave_row<0>(rin, rout, AD, l); break;
        case 1: wave_row<1>(rin, rout, AD, l); break;
        case 2: wave_row<2>(rin, rout, AD, l); break;
        case 3: wave_row<3>(rin, rout, AD, l); break;
    }
}

extern "C" void kernel_launch(void* const* d_in, const int* in_sizes, int n_in,
                              void* d_out, int out_size, void* d_ws, size_t ws_size,
                              hipStream_t stream) {
    const float* in = (const float*)d_in[0];      // [B, E] float32
    float* out = (float*)d_out;                   // [B, E] float32
    const int B = in_sizes[0] / E;                // 8192
    const int grid = (B + 3) / 4;                 // 4 rows (waves) per block
    cascade_kernel<<<grid, 256, 0, stream>>>(in, out, B);
}